// Round 4
// baseline (292.168 us; speedup 1.0000x reference)
//
#include <hip/hip_runtime.h>

typedef __bf16 bf16;
typedef __bf16 bf16x4 __attribute__((ext_vector_type(4)));
typedef __bf16 bf16x8 __attribute__((ext_vector_type(8)));
typedef float f32x4 __attribute__((ext_vector_type(4)));

__device__ inline float bfbits(unsigned u) { return __builtin_bit_cast(float, u); }

__device__ inline bf16x8 cvt8(const float* p) {
  const f32x4* q = (const f32x4*)p;
  f32x4 x0 = q[0];
  f32x4 x1 = q[1];
  bf16x8 a;
  a[0] = (bf16)x0[0]; a[1] = (bf16)x0[1]; a[2] = (bf16)x0[2]; a[3] = (bf16)x0[3];
  a[4] = (bf16)x1[0]; a[5] = (bf16)x1[1]; a[6] = (bf16)x1[2]; a[7] = (bf16)x1[3];
  return a;
}

// ---------------------------------------------------------------------------
// Batched weight prep: f32 W[K][N] -> MFMA B-fragment-ordered bf16.
// dst[((kt*NT+nt)*64 + lane)*8 + j] = W[map(kt*32 + (lane>>4)*8 + j)][nt*16 + (lane&15)]
// mode 1: item-L1 concat map (row<128 ? row : row+256) for [tire|specs|tproj].
// ---------------------------------------------------------------------------
struct WEnt { const float* src; bf16* dst; int K; int N; int mode; int base; };
struct WprepArgs { WEnt e[9]; int nent; int total; float* zb; };

__global__ __launch_bounds__(256) void wprep_all(WprepArgs a) {
  int idx = blockIdx.x * 256 + threadIdx.x;
  if (idx < 128) a.zb[idx] = 0.0f;
  if (idx >= a.total) return;
  int ei = 0;
  while (ei + 1 < a.nent && idx >= a.e[ei + 1].base) ++ei;
  const WEnt E = a.e[ei];
  int li = idx - E.base;
  int lane = li & 63, fi = li >> 6;
  int NT = E.N / 16;
  int kt = fi / NT, nt = fi % NT;
  int krow = kt * 32 + ((lane >> 4) << 3);
  int col = nt * 16 + (lane & 15);
  bf16* d = E.dst + (size_t)li * 8;
#pragma unroll
  for (int j = 0; j < 8; ++j) {
    int r = krow + j;
    if (E.mode == 1) r = (r < 128) ? r : r + 256;
    d[j] = (bf16)E.src[(size_t)r * E.N + col];
  }
}

// ---------------------------------------------------------------------------
// Segment bounds: bound[u] = first index i with hsegs[i] >= u, u in [0,U].
// ---------------------------------------------------------------------------
__global__ __launch_bounds__(256) void seg_bounds(const int* __restrict__ hsegs,
                                                  int* __restrict__ bound, int E, int U) {
  int e = blockIdx.x * 256 + threadIdx.x;
  if (e > E) return;
  if (e == 0) {
    int b = hsegs[0];
    for (int u = 0; u <= b; ++u) bound[u] = 0;
  } else if (e == E) {
    int a = hsegs[E - 1];
    for (int u = a + 1; u <= U; ++u) bound[u] = E;
  } else {
    int a = hsegs[e - 1], b = hsegs[e];
    for (int u = a + 1; u <= b; ++u) bound[u] = e;
  }
}

// ---------------------------------------------------------------------------
// Generic small GEMM (used for brandC / sizeC / text projection).
// ASRC: 0 = f32 [M][K].  OUTM: 0 = bf16 out (+RELU), 2 = f32 plain.
// ---------------------------------------------------------------------------
struct GemmArgs {
  const void* a0;
  const bf16* wfrag; const float* bias;
  void* out; int M;
};

template <int K, int N, int RELU, int OUTM, int NW>
__global__ __launch_bounds__(NW * 64) void gemm_k(GemmArgs g) {
  constexpr int KT = K / 32, NT = N / 16;
  constexpr int TROWS = NW * 32;
  __shared__ bf16 wlds[K * N];
  {
    const uint4* s = (const uint4*)g.wfrag;
    uint4* d = (uint4*)wlds;
    constexpr int CH = K * N * 2 / 16;
    for (int i = threadIdx.x; i < CH; i += NW * 64) d[i] = s[i];
  }
  __syncthreads();

  const int lane = threadIdx.x & 63;
  const int wave = threadIdx.x >> 6;
  const int kgo = (lane >> 4) << 3;
  const int ntiles = (g.M + TROWS - 1) / TROWS;

  for (int tile = blockIdx.x; tile < ntiles; tile += gridDim.x) {
    const int rowbase = tile * TROWS;
    const int rw = rowbase + wave * 16 + (lane & 15);
    const int r0 = min(rw, g.M - 1);
    const int r1 = min(rw + NW * 16, g.M - 1);

    f32x4 acc[2][NT] = {};

#pragma unroll 2
    for (int kt = 0; kt < KT; ++kt) {
      const int kc = kt * 32 + kgo;
      bf16x8 a0 = cvt8((const float*)g.a0 + (size_t)r0 * K + kc);
      bf16x8 a1 = cvt8((const float*)g.a0 + (size_t)r1 * K + kc);
      const bf16x8* bp = ((const bf16x8*)wlds) + kt * NT * 64 + lane;
#pragma unroll
      for (int nt = 0; nt < NT; ++nt) {
        bf16x8 b = bp[nt * 64];
        acc[0][nt] = __builtin_amdgcn_mfma_f32_16x16x32_bf16(a0, b, acc[0][nt], 0, 0, 0);
        acc[1][nt] = __builtin_amdgcn_mfma_f32_16x16x32_bf16(a1, b, acc[1][nt], 0, 0, 0);
      }
    }

    const int colbase = lane & 15;
    const int rgrp = (lane >> 4) * 4;
#pragma unroll
    for (int m = 0; m < 2; ++m) {
      const int rbase = rowbase + m * (NW * 16) + wave * 16 + rgrp;
#pragma unroll
      for (int j = 0; j < 4; ++j) {
        const int r = rbase + j;
        if (r < g.M) {
#pragma unroll
          for (int nt = 0; nt < NT; ++nt) {
            float v = acc[m][nt][j] + g.bias[colbase + nt * 16];
            if constexpr (RELU != 0) v = fmaxf(v, 0.0f);
            if constexpr (OUTM == 2) {
              ((float*)g.out)[(size_t)r * N + colbase + nt * 16] = v;
            } else {
              ((bf16*)g.out)[(size_t)r * N + colbase + nt * 16] = (bf16)v;
            }
          }
        }
      }
    }
  }
}

// ---------------------------------------------------------------------------
// L1 kernel: out[M][128] bf16 = relu(concat @ W1 + bias-term)
// ASRC 2 = item concat [h_tire(128)|specs(64)|tproj(64)], K1=256, BS=1
// ASRC 3 = user concat [h_user(128)|pool(64)], K1=192, BS=0
// LDS = K1*256 bytes only (64KB/48KB) -> 2-3 blocks/CU, 4+ waves/SIMD.
// ---------------------------------------------------------------------------
struct L1Args {
  const void* a0; const void* a1; const void* a2;
  const int* bidx; const int* sidx;
  const float* brandC; const float* sizeC;
  const bf16* wf1; const float* b1;
  bf16* out; int M;
};

template <int K1, int ASRC>
__device__ inline bf16x8 l1_load_a(const L1Args& g, int r, int kc) {
  if constexpr (ASRC == 2) {
    if (kc < 128) return cvt8((const float*)g.a0 + (size_t)r * 128 + kc);
    else if (kc < 192) return cvt8((const float*)g.a1 + (size_t)r * 64 + (kc - 128));
    else return *(const bf16x8*)((const bf16*)g.a2 + (size_t)r * 64 + (kc - 192));
  } else {
    if (kc < 128) return cvt8((const float*)g.a0 + (size_t)r * 128 + kc);
    else return *(const bf16x8*)((const bf16*)g.a1 + (size_t)r * 64 + (kc - 128));
  }
}

template <int K1, int ASRC, int BS>
__global__ __launch_bounds__(512, 4) void l1_k(L1Args g) {
  constexpr int KT1 = K1 / 32;
  constexpr int NW = 8, TROWS = NW * 32;
  __shared__ bf16 w1[K1 * 128];
  {
    const uint4* s = (const uint4*)g.wf1;
    uint4* d = (uint4*)w1;
    for (int i = threadIdx.x; i < K1 * 128 * 2 / 16; i += 512) d[i] = s[i];
  }
  __syncthreads();

  const int lane = threadIdx.x & 63;
  const int wave = threadIdx.x >> 6;
  const int kgo = (lane >> 4) << 3;
  const int colbase = lane & 15;
  const int r4 = (lane >> 4) * 4;
  const int ntiles = (g.M + TROWS - 1) / TROWS;

  for (int tile = blockIdx.x; tile < ntiles; tile += gridDim.x) {
    const int rowbase = tile * TROWS;
    const int rw = rowbase + wave * 16 + colbase;
    const int r0 = min(rw, g.M - 1);
    const int r1 = min(rw + NW * 16, g.M - 1);

    f32x4 acc1[2][8] = {};
#pragma unroll 2
    for (int kt = 0; kt < KT1; ++kt) {
      const int kc = kt * 32 + kgo;
      bf16x8 a0 = l1_load_a<K1, ASRC>(g, r0, kc);
      bf16x8 a1 = l1_load_a<K1, ASRC>(g, r1, kc);
      const bf16x8* bp = ((const bf16x8*)w1) + kt * 8 * 64 + lane;
#pragma unroll
      for (int nt = 0; nt < 8; ++nt) {
        bf16x8 b = bp[nt * 64];
        acc1[0][nt] = __builtin_amdgcn_mfma_f32_16x16x32_bf16(a0, b, acc1[0][nt], 0, 0, 0);
        acc1[1][nt] = __builtin_amdgcn_mfma_f32_16x16x32_bf16(a1, b, acc1[1][nt], 0, 0, 0);
      }
    }

#pragma unroll
    for (int m = 0; m < 2; ++m) {
      const int rbase = rowbase + m * (NW * 16) + wave * 16 + r4;
#pragma unroll
      for (int j = 0; j < 4; ++j) {
        const int r = rbase + j;
        const float* bc = nullptr; const float* sc = nullptr;
        if constexpr (BS != 0) {
          const int rr = min(r, g.M - 1);
          bc = g.brandC + (size_t)g.bidx[rr] * 128;
          sc = g.sizeC + (size_t)g.sidx[rr] * 128;
        }
        if (r < g.M) {
#pragma unroll
          for (int nt = 0; nt < 8; ++nt) {
            const int col = colbase + nt * 16;
            float v = acc1[m][nt][j];
            if constexpr (BS != 0) v += bc[col] + sc[col];
            else v += g.b1[col];
            g.out[(size_t)r * 128 + col] = (bf16)fmaxf(v, 0.0f);
          }
        }
      }
    }
  }
}

// ---------------------------------------------------------------------------
// L2+L3 fused: h[M][128] bf16 -> relu(h@W2+b2) -> @W3+b3 -> l2norm ->
// out f32 [M][64] (+opt bf16 out2). LDS = W2 32KB + handoff 32KB = 64KB.
// W3 fragments read straight from global (16KB, L1/L2-hot).
// ---------------------------------------------------------------------------
struct L23Args {
  const bf16* h; const bf16* wf2; const bf16* wf3;
  const float* b2; const float* b3;
  float* out; bf16* out2; int M;
};

__device__ inline bf16x8 read_afrag(const bf16* hw, int lane, int kt) {
  const int row = lane & 15;
  const int c8 = (kt * 4 + (lane >> 4)) ^ (row & 7);
  return *(const bf16x8*)(hw + row * 128 + c8 * 8);
}

__global__ __launch_bounds__(512, 4) void l23_k(L23Args g) {
  constexpr int NW = 8, TROWS = NW * 32;
  __shared__ bf16 w2[128 * 128];
  __shared__ bf16 ht[NW * 16 * 128];
  {
    const uint4* s = (const uint4*)g.wf2;
    uint4* d = (uint4*)w2;
    for (int i = threadIdx.x; i < 128 * 128 * 2 / 16; i += 512) d[i] = s[i];
  }
  __syncthreads();

  const int lane = threadIdx.x & 63;
  const int wave = threadIdx.x >> 6;
  const int kgo = (lane >> 4) << 3;
  const int colbase = lane & 15;
  const int r4 = (lane >> 4) * 4;
  bf16* hw = ht + wave * (16 * 128);
  const int ntiles = (g.M + TROWS - 1) / TROWS;

  for (int tile = blockIdx.x; tile < ntiles; tile += gridDim.x) {
    const int rowbase = tile * TROWS;
    f32x4 acc3[2][4] = {};

#pragma unroll
    for (int m = 0; m < 2; ++m) {
      const int rw = rowbase + m * (NW * 16) + wave * 16 + colbase;
      const int r = min(rw, g.M - 1);
      bf16x8 a[4];
#pragma unroll
      for (int kt = 0; kt < 4; ++kt)
        a[kt] = *(const bf16x8*)(g.h + (size_t)r * 128 + kt * 32 + kgo);
      f32x4 acc2[8] = {};
#pragma unroll
      for (int kt = 0; kt < 4; ++kt) {
        const bf16x8* bp = ((const bf16x8*)w2) + kt * 8 * 64 + lane;
#pragma unroll
        for (int nt = 0; nt < 8; ++nt)
          acc2[nt] = __builtin_amdgcn_mfma_f32_16x16x32_bf16(a[kt], bp[nt * 64], acc2[nt], 0, 0, 0);
      }
      // stage relu(h2) tile (per-wave, XOR-swizzled)
#pragma unroll
      for (int j = 0; j < 4; ++j) {
        const int row = r4 + j;
#pragma unroll
        for (int nt = 0; nt < 8; ++nt) {
          const int col = colbase + nt * 16;
          float v = fmaxf(acc2[nt][j] + g.b2[col], 0.0f);
          const int c8 = (col >> 3) ^ (row & 7);
          hw[row * 128 + c8 * 8 + (col & 7)] = (bf16)v;
        }
      }
      // L3 (W3 frags from global; 16KB, cache-hot)
#pragma unroll
      for (int kt = 0; kt < 4; ++kt) {
        bf16x8 af = read_afrag(hw, lane, kt);
        const bf16x8* bp = ((const bf16x8*)g.wf3) + kt * 4 * 64 + lane;
#pragma unroll
        for (int nt = 0; nt < 4; ++nt)
          acc3[m][nt] = __builtin_amdgcn_mfma_f32_16x16x32_bf16(af, bp[nt * 64], acc3[m][nt], 0, 0, 0);
      }
    }

    // final epilogue: bias + l2norm + store
#pragma unroll
    for (int m = 0; m < 2; ++m) {
      const int rbase = rowbase + m * (NW * 16) + wave * 16 + r4;
#pragma unroll
      for (int j = 0; j < 4; ++j) {
        float vv[4];
        float ssq = 0.0f;
#pragma unroll
        for (int nt = 0; nt < 4; ++nt) {
          float v = acc3[m][nt][j] + g.b3[colbase + nt * 16];
          vv[nt] = v;
          ssq += v * v;
        }
        ssq += __shfl_xor(ssq, 1);
        ssq += __shfl_xor(ssq, 2);
        ssq += __shfl_xor(ssq, 4);
        ssq += __shfl_xor(ssq, 8);
        const float scale = 1.0f / fmaxf(sqrtf(ssq), 1e-12f);
        const int r = rbase + j;
        if (r < g.M) {
          float* o = g.out + (size_t)r * 64 + colbase;
#pragma unroll
          for (int nt = 0; nt < 4; ++nt) o[nt * 16] = vv[nt] * scale;
          if (g.out2) {
            bf16* o2 = g.out2 + (size_t)r * 64 + colbase;
#pragma unroll
            for (int nt = 0; nt < 4; ++nt) o2[nt * 16] = (bf16)(vv[nt] * scale);
          }
        }
      }
    }
  }
}

// ---------------------------------------------------------------------------
// Segment-mean pooling: 16-lane groups, 4 events/iter in flight x4 unroll
// (16 outstanding 128B gathers per wave).
// ---------------------------------------------------------------------------
__global__ __launch_bounds__(256) void pool_k(const int* __restrict__ hitems,
                                              const int* __restrict__ bound,
                                              const bf16* __restrict__ itemb,
                                              bf16* __restrict__ pool, int U) {
  const int lane = threadIdx.x & 63;
  const int wid = blockIdx.x * 4 + (threadIdx.x >> 6);
  const int stride = gridDim.x * 4;
  const int grp = lane >> 4, li = lane & 15;
  for (int u = wid; u < U; u += stride) {
    const int s = bound[u], e = bound[u + 1];
    f32x4 s0 = {0.f,0.f,0.f,0.f}, s1 = {0.f,0.f,0.f,0.f};
    f32x4 s2 = {0.f,0.f,0.f,0.f}, s3 = {0.f,0.f,0.f,0.f};
    int i = s + grp;
    for (; i + 12 < e; i += 16) {
      int a0 = hitems[i], a1 = hitems[i + 4], a2 = hitems[i + 8], a3 = hitems[i + 12];
      uint2 r0 = *(const uint2*)(itemb + (size_t)a0 * 64 + li * 4);
      uint2 r1 = *(const uint2*)(itemb + (size_t)a1 * 64 + li * 4);
      uint2 r2 = *(const uint2*)(itemb + (size_t)a2 * 64 + li * 4);
      uint2 r3 = *(const uint2*)(itemb + (size_t)a3 * 64 + li * 4);
      s0[0] += bfbits(r0.x << 16); s0[1] += bfbits(r0.x & 0xffff0000u);
      s0[2] += bfbits(r0.y << 16); s0[3] += bfbits(r0.y & 0xffff0000u);
      s1[0] += bfbits(r1.x << 16); s1[1] += bfbits(r1.x & 0xffff0000u);
      s1[2] += bfbits(r1.y << 16); s1[3] += bfbits(r1.y & 0xffff0000u);
      s2[0] += bfbits(r2.x << 16); s2[1] += bfbits(r2.x & 0xffff0000u);
      s2[2] += bfbits(r2.y << 16); s2[3] += bfbits(r2.y & 0xffff0000u);
      s3[0] += bfbits(r3.x << 16); s3[1] += bfbits(r3.x & 0xffff0000u);
      s3[2] += bfbits(r3.y << 16); s3[3] += bfbits(r3.y & 0xffff0000u);
    }
    for (; i < e; i += 4) {
      int a0 = hitems[i];
      uint2 r0 = *(const uint2*)(itemb + (size_t)a0 * 64 + li * 4);
      s0[0] += bfbits(r0.x << 16); s0[1] += bfbits(r0.x & 0xffff0000u);
      s0[2] += bfbits(r0.y << 16); s0[3] += bfbits(r0.y & 0xffff0000u);
    }
#pragma unroll
    for (int c = 0; c < 4; ++c) s0[c] += s1[c] + s2[c] + s3[c];
#pragma unroll
    for (int c = 0; c < 4; ++c) {
      s0[c] += __shfl_xor(s0[c], 16);
      s0[c] += __shfl_xor(s0[c], 32);
    }
    const int cnt = e - s;
    const float inv = (cnt > 0) ? 1.0f / (float)cnt : 0.0f;
    if (grp == 0) {
      bf16x4 o;
      o[0] = (bf16)(s0[0] * inv); o[1] = (bf16)(s0[1] * inv);
      o[2] = (bf16)(s0[2] * inv); o[3] = (bf16)(s0[3] * inv);
      *(bf16x4*)(pool + (size_t)u * 64 + li * 4) = o;
    }
  }
}

// ---------------------------------------------------------------------------
extern "C" void kernel_launch(void* const* d_in, const int* in_sizes, int n_in,
                              void* d_out, int out_size, void* d_ws, size_t ws_size,
                              hipStream_t stream) {
  const float* h_user = (const float*)d_in[0];
  const float* h_tire = (const float*)d_in[1];
  const float* h_brand = (const float*)d_in[2];
  const float* h_size = (const float*)d_in[3];
  const float* specs = (const float*)d_in[4];
  const float* text = (const float*)d_in[5];
  const int* bidx = (const int*)d_in[6];
  const int* sidx = (const int*)d_in[7];
  const int* hitems = (const int*)d_in[8];
  const int* hsegs = (const int*)d_in[9];
  const float* W_tp = (const float*)d_in[10]; const float* b_tp = (const float*)d_in[11];
  const float* W_i1 = (const float*)d_in[12]; const float* b_i1 = (const float*)d_in[13];
  const float* W_i2 = (const float*)d_in[14]; const float* b_i2 = (const float*)d_in[15];
  const float* W_i3 = (const float*)d_in[16]; const float* b_i3 = (const float*)d_in[17];
  const float* W_u1 = (const float*)d_in[18]; const float* b_u1 = (const float*)d_in[19];
  const float* W_u2 = (const float*)d_in[20]; const float* b_u2 = (const float*)d_in[21];
  const float* W_u3 = (const float*)d_in[22]; const float* b_u3 = (const float*)d_in[23];

  const int U = in_sizes[0] / 128;   // 100000
  const int T = in_sizes[4] / 64;    // 100000
  const int E = in_sizes[8];         // 2000000

  char* ws = (char*)d_ws;
  size_t off = 0;
  auto alloc = [&](size_t bytes) -> char* {
    char* p = ws + off;
    off += (bytes + 255) & ~(size_t)255;
    return p;
  };
  bf16* wf_tp  = (bf16*)alloc(384 * 64 * 2);
  bf16* wf_i1a = (bf16*)alloc(256 * 128 * 2);
  bf16* wf_ib  = (bf16*)alloc(128 * 128 * 2);
  bf16* wf_is  = (bf16*)alloc(128 * 128 * 2);
  bf16* wf_i2  = (bf16*)alloc(128 * 128 * 2);
  bf16* wf_i3  = (bf16*)alloc(128 * 64 * 2);
  bf16* wf_u1  = (bf16*)alloc(192 * 128 * 2);
  bf16* wf_u2  = (bf16*)alloc(128 * 128 * 2);
  bf16* wf_u3  = (bf16*)alloc(128 * 64 * 2);
  float* zb    = (float*)alloc(128 * 4);
  float* brandC = (float*)alloc(100 * 128 * 4);
  float* sizeC  = (float*)alloc(500 * 128 * 4);
  bf16* tpbuf = (bf16*)alloc((size_t)T * 64 * 2);
  bf16* h1b   = (bf16*)alloc((size_t)T * 128 * 2);
  bf16* pool  = (bf16*)alloc((size_t)U * 64 * 2);
  bf16* itemb = (bf16*)alloc((size_t)T * 64 * 2);
  int* bound  = (int*)alloc((size_t)(U + 1) * 4);
  (void)ws_size; (void)n_in; (void)out_size;

  // --- batched weight prep ---
  WprepArgs wa = {};
  auto addent = [&](int i, const float* src, bf16* dst, int K, int N, int mode, int& run) {
    wa.e[i] = {src, dst, K, N, mode, run};
    run += (K / 32) * (N / 16) * 64;
  };
  int run = 0;
  addent(0, W_tp, wf_tp, 384, 64, 0, run);
  addent(1, W_i1, wf_i1a, 256, 128, 1, run);            // [tire|specs|tproj] rows
  addent(2, W_i1 + 128 * 128, wf_ib, 128, 128, 0, run); // brand rows
  addent(3, W_i1 + 256 * 128, wf_is, 128, 128, 0, run); // size rows
  addent(4, W_i2, wf_i2, 128, 128, 0, run);
  addent(5, W_i3, wf_i3, 128, 64, 0, run);
  addent(6, W_u1, wf_u1, 192, 128, 0, run);
  addent(7, W_u2, wf_u2, 128, 128, 0, run);
  addent(8, W_u3, wf_u3, 128, 64, 0, run);
  wa.nent = 9; wa.total = run; wa.zb = zb;
  wprep_all<<<(run + 255) / 256, 256, 0, stream>>>(wa);

  seg_bounds<<<(E + 256) / 256, 256, 0, stream>>>(hsegs, bound, E, U);

  {  // brandC[100][128] = h_brand @ W_i1[128:256] + b_i1   (bias folded here)
    GemmArgs a = {}; a.a0 = h_brand; a.wfrag = wf_ib; a.bias = b_i1; a.out = brandC; a.M = 100;
    gemm_k<128, 128, 0, 2, 4><<<1, 256, 0, stream>>>(a);
  }
  {  // sizeC[500][128] = h_size @ W_i1[256:384]   (zero bias)
    GemmArgs a = {}; a.a0 = h_size; a.wfrag = wf_is; a.bias = zb; a.out = sizeC; a.M = 500;
    gemm_k<128, 128, 0, 2, 4><<<4, 256, 0, stream>>>(a);
  }
  {  // text projection: [T,384] f32 @ [384,64] -> relu -> tpbuf bf16
    GemmArgs a = {}; a.a0 = text; a.wfrag = wf_tp; a.bias = b_tp; a.out = tpbuf; a.M = T;
    gemm_k<384, 64, 1, 0, 4><<<(T + 127) / 128, 256, 0, stream>>>(a);
  }

  float* out_user = (float*)d_out;
  float* out_item = out_user + (size_t)U * 64;
  const int tiles256 = (T + 255) / 256;   // == (U + 255) / 256 here

  {  // item L1
    L1Args a = {};
    a.a0 = h_tire; a.a1 = specs; a.a2 = tpbuf;
    a.bidx = bidx; a.sidx = sidx; a.brandC = brandC; a.sizeC = sizeC;
    a.wf1 = wf_i1a; a.b1 = zb; a.out = h1b; a.M = T;
    l1_k<256, 2, 1><<<tiles256, 512, 0, stream>>>(a);
  }
  {  // item L2+L3 + l2norm
    L23Args a = {};
    a.h = h1b; a.wf2 = wf_i2; a.wf3 = wf_i3; a.b2 = b_i2; a.b3 = b_i3;
    a.out = out_item; a.out2 = itemb; a.M = T;
    l23_k<<<tiles256, 512, 0, stream>>>(a);
  }

  pool_k<<<(U + 3) / 4, 256, 0, stream>>>(hitems, bound, itemb, pool, U);

  {  // user L1
    L1Args a = {};
    a.a0 = h_user; a.a1 = pool;
    a.wf1 = wf_u1; a.b1 = b_u1; a.out = h1b; a.M = U;
    l1_k<192, 3, 0><<<(U + 255) / 256, 512, 0, stream>>>(a);
  }
  {  // user L2+L3 + l2norm
    L23Args a = {};
    a.h = h1b; a.wf2 = wf_u2; a.wf3 = wf_u3; a.b2 = b_u2; a.b3 = b_u3;
    a.out = out_user; a.out2 = nullptr; a.M = U;
    l23_k<<<(U + 255) / 256, 512, 0, stream>>>(a);
  }
}